// Round 1
// baseline (196.677 us; speedup 1.0000x reference)
//
#include <hip/hip_runtime.h>

// ---------------------------------------------------------------------------
// SelfAttentionLayer: out[b,s,c*16+h] = softmax_k( (q.k)/32 masked ) @ v
// R7: pipeline phase-1 GEMM. BK 64->32 with double-buffered Xs/Ws at the SAME
// 38 KB LDS footprint (4 blocks/CU preserved). Each K-step issues next tile's
// global_load_lds BEFORE computing the current one; counted s_waitcnt vmcnt(N)
// (never 0 in-loop) + raw s_barrier replaces the __syncthreads() full drain
// that serialized staging against compute (T3 minimum-2-phase + T4).
// ---------------------------------------------------------------------------

typedef unsigned short u16;
typedef unsigned int u32;
typedef __attribute__((ext_vector_type(8))) short short8;
typedef __attribute__((ext_vector_type(4))) short short4v;
typedef __attribute__((ext_vector_type(4))) float floatx4;

#if __has_builtin(__builtin_amdgcn_mfma_f32_16x16x16bf16_1k)
#define MFMA16(A, B, C) __builtin_amdgcn_mfma_f32_16x16x16bf16_1k(A, B, C, 0, 0, 0)
#elif __has_builtin(__builtin_amdgcn_mfma_f32_16x16x16_bf16)
#define MFMA16(A, B, C) __builtin_amdgcn_mfma_f32_16x16x16_bf16(A, B, C, 0, 0, 0)
#else
__device__ __forceinline__ floatx4 mfma16_asm(short4v a, short4v b, floatx4 c) {
  floatx4 d;
  asm volatile("v_mfma_f32_16x16x16_bf16 %0, %1, %2, %3"
               : "=v"(d) : "v"(a), "v"(b), "v"(c));
  return d;
}
#define MFMA16(A, B, C) mfma16_asm(A, B, C)
#endif

#if __has_builtin(__builtin_amdgcn_exp2f)
#define EXP2(x) __builtin_amdgcn_exp2f(x)
#else
#define EXP2(x) __expf((x) * 0.6931471805599453f)
#endif

#define QSCALE 0.045084220f  // log2(e)/32, folded into Q

__device__ __forceinline__ u16 f2bf(float f) {
  union { float f; u32 u; } x; x.f = f;
  u32 r = x.u + 0x7fffu + ((x.u >> 16) & 1u);  // RNE
  return (u16)(r >> 16);
}
__device__ __forceinline__ float bf2f(u16 u) {
  union { u32 u; float f; } x; x.u = ((u32)u) << 16;
  return x.f;
}

// async global->LDS, 16B per lane; LDS dest = wave-uniform base + lane*16
__device__ __forceinline__ void gload16(const void* g, void* l) {
  typedef __attribute__((address_space(1))) const unsigned int gq;
  typedef __attribute__((address_space(3))) unsigned int lq;
  __builtin_amdgcn_global_load_lds((gq*)(size_t)g, (lq*)(size_t)l, 16, 0, 0);
}

#define GK 1024
#define QKS 20   // Qs/Ks row stride (u16): 8B-aligned frags, conflict-free
#define VTS 264  // Vt row stride (u16): 2-way-max banks (free)

// ---------------------------------------------------------------------------
// Merged cast f32 -> bf16: X (8192 blocks), Wq/Wk/Wv (1024 blocks each)
// ---------------------------------------------------------------------------
__global__ __launch_bounds__(256) void cast_all(const float* __restrict__ x,
                                                const float* __restrict__ wq,
                                                const float* __restrict__ wk,
                                                const float* __restrict__ wv,
                                                u16* __restrict__ XB,
                                                u16* __restrict__ WB) {
  int bid = blockIdx.x;
  const float* src; u16* dst; int off;
  if (bid < 8192)       { src = x;  dst = XB;                 off = bid; }
  else if (bid < 9216)  { src = wq; dst = WB;                 off = bid - 8192; }
  else if (bid < 10240) { src = wk; dst = WB + 1024 * 1024;   off = bid - 9216; }
  else                  { src = wv; dst = WB + 2 * 1024 * 1024; off = bid - 10240; }
  int i = (off * 256 + threadIdx.x) * 4;
  float4 v = *(const float4*)(src + i);
  u32 lo = (u32)f2bf(v.x) | ((u32)f2bf(v.y) << 16);
  u32 hi = (u32)f2bf(v.z) | ((u32)f2bf(v.w) << 16);
  uint2 o; o.x = lo; o.y = hi;
  *(uint2*)(dst + i) = o;
}

// ---------------------------------------------------------------------------
// Attn kt-loop (R5-verified math, LDS sources): S^T = MFMA(K, Qscaled);
// p = exp2(st) trunc-packed via v_perm; l via MFMA(ones,p); O^T += MFMA(V^T,p)
// ---------------------------------------------------------------------------
template <bool MASKED>
__device__ __forceinline__ void attn_loop(const u16* __restrict__ Ks,
                                          const u16* __restrict__ Vt,
                                          const short4v* bq, const float* mqv,
                                          const float* m_s,
                                          floatx4* oacc, floatx4* lacc,
                                          int col, int quad) {
  const short4v ones = {(short)0x3F80, (short)0x3F80, (short)0x3F80, (short)0x3F80};
#pragma unroll 4
  for (int kt = 0; kt < 16; kt++) {
    const int kb = kt * 16;
    short4v ak = *(const short4v*)(Ks + (kb + col) * QKS + quad * 4);
    short4v av = *(const short4v*)(Vt + col * VTS + kb + quad * 4);
    float mk[4];
    if (MASKED) {
#pragma unroll
      for (int i = 0; i < 4; i++) mk[i] = m_s[kb + quad * 4 + i];
    }
#pragma unroll
    for (int qt = 0; qt < 4; qt++) {
      floatx4 z = {0.f, 0.f, 0.f, 0.f};
      floatx4 st = MFMA16(ak, bq[qt], z);
      float e[4];
#pragma unroll
      for (int i = 0; i < 4; i++) {
        e[i] = EXP2(st[i]);
        if (MASKED) e[i] = (mqv[qt] * mk[i] > 0.f) ? e[i] : 0.f;
      }
      union { u32 u[2]; short4v s; } pk;
      pk.u[0] = __builtin_amdgcn_perm(__float_as_uint(e[1]), __float_as_uint(e[0]), 0x07060302u);
      pk.u[1] = __builtin_amdgcn_perm(__float_as_uint(e[3]), __float_as_uint(e[2]), 0x07060302u);
      lacc[qt] = MFMA16(ones, pk.s, lacc[qt]);
      oacc[qt] = MFMA16(av, pk.s, oacc[qt]);
    }
  }
}

// ---------------------------------------------------------------------------
// Fused kernel. Block = (c = bid>>5, b = bid&31)  [same-b blocks -> same XCD
// via bid%8 = b%8: X[b] (512 KB) stays L2-resident].
// Phase 1 (GEMM, R7-pipelined): Q|K|V[256,48] = X[b] @ Wslice^T.
//   BK=32, double-buffered: Xs 2x[256][32] @0/@8192, Ws 2x[48][32] @16384/@17920.
//   Per iter: issue DMA(t+1) -> counted vmcnt -> s_barrier -> 7 ds_read_b128 +
//   12 MFMA -> lgkmcnt(0) -> s_barrier. XOR swizzle: LDS chunk = (k>>3)^(row&3),
//   applied on the pre-swizzled global source (gload_lds dest stays linear).
// Phase 2: Q,K (stride-20) + V^T (stride-264) through LDS -> attn_loop.
// LDS: GEMM 38 KB / attn 28.9 KB share smem; +1 KB m_s = 39.9 KB -> 4 blk/CU.
// ---------------------------------------------------------------------------
__global__ __launch_bounds__(256) void fused_qkv_attn(const u16* __restrict__ XB,
                                                      const u16* __restrict__ WB,
                                                      const float* __restrict__ mask,
                                                      float* __restrict__ out) {
  __shared__ __align__(16) u16 smem[19456];
  // GEMM: Xs0@0, Xs1@8192, Ws0@16384, Ws1@17920
  // attn: Qs@0 (256*20), Ks@5120, Vt@10240 (16*264), l_s@14464 (256 f32),
  //       ot overlays @0 (16*257 f32)
  __shared__ float m_s[256];

  const int bid = blockIdx.x;
  const int b = bid & 31;
  const int c = bid >> 5;
  const int t = threadIdx.x;
  const int wave = t >> 6;
  const int lane = t & 63;
  const int col = lane & 15;
  const int quad = lane >> 4;

  u16* const Xs0 = smem;
  u16* const Xs1 = smem + 8192;
  u16* const Ws0 = smem + 16384;
  u16* const Ws1 = smem + 17920;

  float mv = mask[b * 256 + t];
  m_s[t] = mv;
  const int allones = __syncthreads_and(mv > 0.f);

  // ---------------- phase 1: pipelined GEMM ----------------
  // Staging (per wave, per 32-k tile): 4 X gload16 (16 rows each) + 1 W
  // gload16 for waves 0..2 (wave w stages Wq/Wk/Wv rows respectively).
  const int rl = lane >> 2;            // row within 16-row group
  const int ch = lane & 3;             // dest k-chunk (8 u16)
  const int sch = ch ^ (rl & 3);       // XOR-swizzled source chunk
  const size_t xsrc = ((size_t)b * 256 + wave * 64 + rl) * GK + sch * 8;
  const int xdst = wave * 2048;        // (wave*64 rows)*32; + g*512
  size_t wsrc = 0;
  if (wave < 3)
    wsrc = ((size_t)wave * 1024 + c * 16 + rl) * GK + sch * 8;  // Q/K/V row block
  const int wdst = wave * 512;         // (wave*16 rows)*32

  floatx4 acc[4][3] = {};  // [mt][nt]: m = wave*64+mt*16, n (0=Q,1=K,2=V)

  const int ropos = (quad ^ (col & 3)) * 8;            // read-side un-swizzle
  const int arow = (wave * 64 + col) * 32 + ropos;     // + mt*512

  // prologue: stage tile 0 into buf0
#pragma unroll
  for (int g = 0; g < 4; g++)
    gload16(XB + xsrc + (size_t)g * 16 * GK, Xs0 + xdst + g * 512);
  if (wave < 3) gload16(WB + wsrc, Ws0 + wdst);

#pragma unroll 2
  for (int tt = 0; tt < 32; tt++) {
    u16* const Xc = (tt & 1) ? Xs1 : Xs0;
    u16* const Wc = (tt & 1) ? Ws1 : Ws0;
    u16* const Xn = (tt & 1) ? Xs0 : Xs1;
    u16* const Wn = (tt & 1) ? Ws0 : Ws1;

    if (tt < 31) {
      const int k0n = (tt + 1) * 32;
#pragma unroll
      for (int g = 0; g < 4; g++)
        gload16(XB + xsrc + (size_t)g * 16 * GK + k0n, Xn + xdst + g * 512);
      if (wave < 3) {
        gload16(WB + wsrc + k0n, Wn + wdst);
        asm volatile("s_waitcnt vmcnt(5)" ::: "memory");  // prev stage done
      } else {
        asm volatile("s_waitcnt vmcnt(4)" ::: "memory");
      }
    } else {
      asm volatile("s_waitcnt vmcnt(0)" ::: "memory");    // last tile: drain
    }
    __builtin_amdgcn_sched_barrier(0);
    __builtin_amdgcn_s_barrier();      // all waves' DMA for cur tile landed
    __builtin_amdgcn_sched_barrier(0); // keep ds_reads below the barrier

    short8 af[4], bf[3];
#pragma unroll
    for (int mt = 0; mt < 4; mt++)
      af[mt] = *(const short8*)(Xc + arow + mt * 512);
#pragma unroll
    for (int nt = 0; nt < 3; nt++)
      bf[nt] = *(const short8*)(Wc + (nt * 16 + col) * 32 + ropos);
#pragma unroll
    for (int mt = 0; mt < 4; mt++)
#pragma unroll
      for (int nt = 0; nt < 3; nt++)
        acc[mt][nt] = __builtin_amdgcn_mfma_f32_16x16x32_bf16(af[mt], bf[nt], acc[mt][nt], 0, 0, 0);

    asm volatile("s_waitcnt lgkmcnt(0)" ::: "memory");  // my reads of cur done
    __builtin_amdgcn_sched_barrier(0);
    __builtin_amdgcn_s_barrier();      // cur buf safe to overwrite next iter
  }

  // ---------------- Q/K/V -> LDS ----------------
  __syncthreads();  // full drain before overlay
  u16* Qs = smem;               // [256][QKS]
  u16* Ks = smem + 5120;        // [256][QKS]
  u16* Vt = smem + 10240;       // [16][VTS]
  float* l_s = (float*)(smem + 14464);

  // C/D layout: row = m-base + quad*4 + r, col(head feature) = lane&15
#pragma unroll
  for (int mt = 0; mt < 4; mt++) {
    const int row = wave * 64 + mt * 16 + quad * 4;
#pragma unroll
    for (int r = 0; r < 4; r++) {
      Qs[(row + r) * QKS + col] = f2bf(acc[mt][0][r] * QSCALE);
      Ks[(row + r) * QKS + col] = f2bf(acc[mt][1][r]);
      Vt[col * VTS + row + r] = f2bf(acc[mt][2][r]);
    }
  }
  __syncthreads();

  // ---------------- phase 2: attention ----------------
  const int q0 = wave * 64;

  short4v bq[4];
#pragma unroll
  for (int qt = 0; qt < 4; qt++)
    bq[qt] = *(const short4v*)(Qs + (q0 + qt * 16 + col) * QKS + quad * 4);

  float mqv[4];
#pragma unroll
  for (int qt = 0; qt < 4; qt++) mqv[qt] = m_s[q0 + qt * 16 + col];

  floatx4 oacc[4] = {};
  floatx4 lacc[4] = {};

  if (allones)
    attn_loop<false>(Ks, Vt, bq, mqv, m_s, oacc, lacc, col, quad);
  else
    attn_loop<true>(Ks, Vt, bq, mqv, m_s, oacc, lacc, col, quad);

  __syncthreads();  // all waves out of attn_loop before ot overlays Qs/Ks
  float* ot = (float*)smem;  // [16][257] = 16.4 KB, inside Qs+Ks (20.5 KB)

#pragma unroll
  for (int qt = 0; qt < 4; qt++) {
    if (quad == 0) l_s[q0 + qt * 16 + col] = lacc[qt][0];
#pragma unroll
    for (int r = 0; r < 4; r++)
      ot[(quad * 4 + r) * 257 + q0 + qt * 16 + col] = oacc[qt][r];
  }
  __syncthreads();

  // epilogue: thread t owns q-row t; 64B coalesced f32 store
  float l = l_s[t];
  float* op = out + ((size_t)b * 256 + t) * 1024 + c * 16;
  float o[16];
  if (allones || l > 0.f) {
    float inv = 1.0f / l;
#pragma unroll
    for (int h = 0; h < 16; h++) o[h] = ot[h * 257 + t] * inv;
  } else {
    // fully-masked row: reference softmax of uniform -1e9 -> mean of V
#pragma unroll
    for (int h = 0; h < 16; h++) o[h] = 0.f;
    for (int k = 0; k < 256; k++)
#pragma unroll
      for (int h = 0; h < 16; h++) o[h] += bf2f(Vt[h * VTS + k]);
#pragma unroll
    for (int h = 0; h < 16; h++) o[h] *= (1.0f / 256.0f);
  }
#pragma unroll
  for (int g = 0; g < 4; g++) {
    float4 r;
    r.x = o[g * 4 + 0]; r.y = o[g * 4 + 1]; r.z = o[g * 4 + 2]; r.w = o[g * 4 + 3];
    *(float4*)(op + g * 4) = r;
  }
}

// ---------------------------------------------------------------------------
// Launch
// ---------------------------------------------------------------------------
extern "C" void kernel_launch(void* const* d_in, const int* in_sizes, int n_in,
                              void* d_out, int out_size, void* d_ws, size_t ws_size,
                              hipStream_t stream) {
  const float* x    = (const float*)d_in[0];  // [32,256,1024]
  const float* mask = (const float*)d_in[1];  // [32,256]
  const float* Wq   = (const float*)d_in[2];  // [1024,1024]
  const float* Wk   = (const float*)d_in[3];
  const float* Wv   = (const float*)d_in[4];
  float* out = (float*)d_out;

  u16* XB = (u16*)d_ws;                       // [8192][1024] bf16
  u16* WB = XB + (size_t)8192 * 1024;         // [3072][1024] (Wq,Wk,Wv stacked)

  cast_all<<<11264, 256, 0, stream>>>(x, Wq, Wk, Wv, XB, WB);
  fused_qkv_attn<<<2048, 256, 0, stream>>>(XB, WB, mask, out);
}

// Round 2
// 165.177 us; speedup vs baseline: 1.1907x; 1.1907x over previous
//
#include <hip/hip_runtime.h>

// ---------------------------------------------------------------------------
// SelfAttentionLayer: out[b,s,c*16+h] = softmax_k( (q.k)/32 masked ) @ v
// R8: G=2 heads per block (grid 1024, 512 thr / 8 waves). Phase-1 staging is
// L2-BW-bound (1.27 GB @ 34.5 TB/s = 37 us floor at G=1); grouping 2 heads
// halves the X panel re-staging -> 737 MB (~21 us floor). GEMM reverts to the
// R6-proven single-buffer BK=64 structure + conflict-free 64-wide XOR swizzle
// (R7's BK=32 swizzle was 4-way-conflicted: wrong key). Attention phase runs
// twice (head 0, head 1) with the R5-verified math, qt=2 per wave.
// ---------------------------------------------------------------------------

typedef unsigned short u16;
typedef unsigned int u32;
typedef __attribute__((ext_vector_type(8))) short short8;
typedef __attribute__((ext_vector_type(4))) short short4v;
typedef __attribute__((ext_vector_type(4))) float floatx4;

#if __has_builtin(__builtin_amdgcn_mfma_f32_16x16x16bf16_1k)
#define MFMA16(A, B, C) __builtin_amdgcn_mfma_f32_16x16x16bf16_1k(A, B, C, 0, 0, 0)
#elif __has_builtin(__builtin_amdgcn_mfma_f32_16x16x16_bf16)
#define MFMA16(A, B, C) __builtin_amdgcn_mfma_f32_16x16x16_bf16(A, B, C, 0, 0, 0)
#else
__device__ __forceinline__ floatx4 mfma16_asm(short4v a, short4v b, floatx4 c) {
  floatx4 d;
  asm volatile("v_mfma_f32_16x16x16_bf16 %0, %1, %2, %3"
               : "=v"(d) : "v"(a), "v"(b), "v"(c));
  return d;
}
#define MFMA16(A, B, C) mfma16_asm(A, B, C)
#endif

#if __has_builtin(__builtin_amdgcn_exp2f)
#define EXP2(x) __builtin_amdgcn_exp2f(x)
#else
#define EXP2(x) __expf((x) * 0.6931471805599453f)
#endif

#define QSCALE 0.045084220f  // log2(e)/32, folded into Q

__device__ __forceinline__ u16 f2bf(float f) {
  union { float f; u32 u; } x; x.f = f;
  u32 r = x.u + 0x7fffu + ((x.u >> 16) & 1u);  // RNE
  return (u16)(r >> 16);
}
__device__ __forceinline__ float bf2f(u16 u) {
  union { u32 u; float f; } x; x.u = ((u32)u) << 16;
  return x.f;
}

// async global->LDS, 16B per lane; LDS dest = wave-uniform base + lane*16
__device__ __forceinline__ void gload16(const void* g, void* l) {
  typedef __attribute__((address_space(1))) const unsigned int gq;
  typedef __attribute__((address_space(3))) unsigned int lq;
  __builtin_amdgcn_global_load_lds((gq*)(size_t)g, (lq*)(size_t)l, 16, 0, 0);
}

#define GK 1024
#define QKS 20   // Qs/Ks row stride (u16): 8B-aligned frags, conflict-free
#define VTS 264  // Vt row stride (u16): 2-way-max banks (free)

// ---------------------------------------------------------------------------
// Merged cast f32 -> bf16: X (8192 blocks), Wq/Wk/Wv (1024 blocks each)
// ---------------------------------------------------------------------------
__global__ __launch_bounds__(256) void cast_all(const float* __restrict__ x,
                                                const float* __restrict__ wq,
                                                const float* __restrict__ wk,
                                                const float* __restrict__ wv,
                                                u16* __restrict__ XB,
                                                u16* __restrict__ WB) {
  int bid = blockIdx.x;
  const float* src; u16* dst; int off;
  if (bid < 8192)       { src = x;  dst = XB;                 off = bid; }
  else if (bid < 9216)  { src = wq; dst = WB;                 off = bid - 8192; }
  else if (bid < 10240) { src = wk; dst = WB + 1024 * 1024;   off = bid - 9216; }
  else                  { src = wv; dst = WB + 2 * 1024 * 1024; off = bid - 10240; }
  int i = (off * 256 + threadIdx.x) * 4;
  float4 v = *(const float4*)(src + i);
  u32 lo = (u32)f2bf(v.x) | ((u32)f2bf(v.y) << 16);
  u32 hi = (u32)f2bf(v.z) | ((u32)f2bf(v.w) << 16);
  uint2 o; o.x = lo; o.y = hi;
  *(uint2*)(dst + i) = o;
}

// ---------------------------------------------------------------------------
// Attn kt-loop (R5-verified math, LDS sources): S^T = MFMA(K, Qscaled);
// p = exp2(st) trunc-packed via v_perm; l via MFMA(ones,p); O^T += MFMA(V^T,p)
// qt=2: each of the 8 waves owns a 32-row q-strip.
// ---------------------------------------------------------------------------
template <bool MASKED>
__device__ __forceinline__ void attn_loop2(const u16* __restrict__ Ks,
                                           const u16* __restrict__ Vt,
                                           const short4v* bq, const float* mqv,
                                           const float* m_s,
                                           floatx4* oacc, floatx4* lacc,
                                           int col, int quad) {
  const short4v ones = {(short)0x3F80, (short)0x3F80, (short)0x3F80, (short)0x3F80};
#pragma unroll 4
  for (int kt = 0; kt < 16; kt++) {
    const int kb = kt * 16;
    short4v ak = *(const short4v*)(Ks + (kb + col) * QKS + quad * 4);
    short4v av = *(const short4v*)(Vt + col * VTS + kb + quad * 4);
    float mk[4];
    if (MASKED) {
#pragma unroll
      for (int i = 0; i < 4; i++) mk[i] = m_s[kb + quad * 4 + i];
    }
#pragma unroll
    for (int qt = 0; qt < 2; qt++) {
      floatx4 z = {0.f, 0.f, 0.f, 0.f};
      floatx4 st = MFMA16(ak, bq[qt], z);
      float e[4];
#pragma unroll
      for (int i = 0; i < 4; i++) {
        e[i] = EXP2(st[i]);
        if (MASKED) e[i] = (mqv[qt] * mk[i] > 0.f) ? e[i] : 0.f;
      }
      union { u32 u[2]; short4v s; } pk;
      pk.u[0] = __builtin_amdgcn_perm(__float_as_uint(e[1]), __float_as_uint(e[0]), 0x07060302u);
      pk.u[1] = __builtin_amdgcn_perm(__float_as_uint(e[3]), __float_as_uint(e[2]), 0x07060302u);
      lacc[qt] = MFMA16(ones, pk.s, lacc[qt]);
      oacc[qt] = MFMA16(av, pk.s, oacc[qt]);
    }
  }
}

// ---------------------------------------------------------------------------
// Fused kernel. Block = (c0 = (bid>>5)*2 heads, b = bid&31); grid 1024 =
// 256 CU x 2 blocks/CU x 2 exact rounds. Same-b blocks -> same XCD (bid%8 =
// b%8): X[b] (512 KB) stays L2-resident, 4 b's = 2 MB per XCD L2.
// Phase 1 (GEMM): [256,96] = X[b][256,1024] @ Wslice[96,1024]^T.
//   8 waves, wave w owns 32-row strip: acc[2 mt][6 nt] (nt = head*3 + {Q,K,V}).
//   BK=64 single-buffer, R6 structure: sync / 4+{1,2} gload16 / sync / compute.
//   XOR swizzle (proven): phys chunk p of row holds logical p^(row&7).
// Phase 2 (x2 heads, sequential): Q,K (stride-20) + V^T (stride-264) in LDS ->
//   attn_loop2 -> ot -> epilogue store (thread t -> row t>>1, 8 floats).
// LDS: GEMM Xs[256][64]@0 + Ws[96][64]@32768B = 45 KB; attn (29.3 KB) overlays
// Xs; +1 KB m_s = 46 KB -> 2 blocks/CU (VGPR-capped at 128 anyway).
// ---------------------------------------------------------------------------
__global__ __launch_bounds__(512, 4) void fused_qkv_attn(const u16* __restrict__ XB,
                                                         const u16* __restrict__ WB,
                                                         const float* __restrict__ mask,
                                                         float* __restrict__ out) {
  __shared__ __align__(16) u16 smem[22528];  // 45056 B
  // GEMM: Xs@0 (256*64), Ws@16384 (96*64)
  // attn: Qs@0 (256*20), Ks@5120, Vt@10240 (16*264), l_s@14464 (256 f32),
  //       ot overlays @0 (16*257 f32)
  __shared__ float m_s[256];

  const int bid = blockIdx.x;
  const int b = bid & 31;
  const int c0 = (bid >> 5) * 2;       // first of 2 heads
  const int t = threadIdx.x;
  const int wave = t >> 6;             // 0..7
  const int lane = t & 63;
  const int col = lane & 15;
  const int quad = lane >> 4;

  u16* const Xs = smem;
  u16* const Ws = smem + 16384;

  float mv = (t < 256) ? mask[b * 256 + t] : 1.0f;
  if (t < 256) m_s[t] = mv;
  const int allones = __syncthreads_and(mv > 0.f);

  // ---------------- phase 1: GEMM ----------------
  const int r_loc = lane >> 3;          // row within 8-row gload group
  const int sch = (lane & 7) ^ r_loc;   // XOR-swizzled source k-chunk

  // X: wave w stages its own 32 rows (4 gload16 of 8 rows each)
  const size_t xsrc = ((size_t)b * 256 + wave * 32 + r_loc) * GK + sch * 8;
  const int xdst = wave * 2048;         // u16: (wave*32 rows)*64; + g*512

  // W: 12 groups of 8 rows; group g -> nt = g>>1 (nt = head*3 + mat),
  // WB row = (nt%3)*1024 + (c0 + nt/3)*16 + (g&1)*8 + r_loc.
  // wave w stages group w; waves 0-3 also stage group 8+w.
  const int gA = wave;
  const int ntA = gA >> 1;
  const size_t wsrcA =
      ((size_t)((ntA % 3) * 1024 + (c0 + ntA / 3) * 16 + (gA & 1) * 8 + r_loc)) * GK + sch * 8;
  size_t wsrcB = 0;
  const int gB = 8 + wave;
  if (wave < 4) {
    const int ntB = gB >> 1;
    wsrcB = ((size_t)((ntB % 3) * 1024 + (c0 + ntB / 3) * 16 + (gB & 1) * 8 + r_loc)) * GK + sch * 8;
  }

  floatx4 acc[2][6] = {};  // [mt][nt]: m = wave*32+mt*16; nt = head*3+{Q,K,V}

  for (int k0 = 0; k0 < GK; k0 += 64) {
    __syncthreads();  // prev iter's ds_reads done before DMA overwrites
#pragma unroll
    for (int g = 0; g < 4; g++)
      gload16(XB + xsrc + (size_t)g * 8 * GK + k0, Xs + xdst + g * 512);
    gload16(WB + wsrcA + k0, Ws + gA * 512);
    if (wave < 4) gload16(WB + wsrcB + k0, Ws + gB * 512);
    __syncthreads();  // tile landed (full drain, R6-proven)
#pragma unroll
    for (int kk = 0; kk < 2; kk++) {
      const int pos = ((kk * 4 + quad) ^ (col & 7)) * 8;
      short8 af[2], bf[6];
#pragma unroll
      for (int mt = 0; mt < 2; mt++)
        af[mt] = *(const short8*)(Xs + (wave * 32 + mt * 16 + col) * 64 + pos);
#pragma unroll
      for (int nt = 0; nt < 6; nt++)
        bf[nt] = *(const short8*)(Ws + (nt * 16 + col) * 64 + pos);
#pragma unroll
      for (int mt = 0; mt < 2; mt++)
#pragma unroll
        for (int nt = 0; nt < 6; nt++)
          acc[mt][nt] = __builtin_amdgcn_mfma_f32_16x16x32_bf16(af[mt], bf[nt], acc[mt][nt], 0, 0, 0);
    }
  }

  // ---------------- phase 2: attention, 2 heads sequentially ----------------
  u16* const Qs = smem;               // [256][QKS]
  u16* const Ks = smem + 5120;        // [256][QKS]
  u16* const Vt = smem + 10240;       // [16][VTS]
  float* const l_s = (float*)(smem + 14464);
  float* const ot = (float*)smem;     // [16][257] f32, overlays Qs+Ks

#pragma unroll      // full unroll: h must be compile-time (static acc indices)
  for (int h = 0; h < 2; h++) {
    __syncthreads();  // h=0: GEMM reads done; h=1: prev ot/Vt reads done

    // C/D layout: row = m-base + quad*4 + r, col(head feature) = lane&15
#pragma unroll
    for (int mt = 0; mt < 2; mt++) {
      const int row = wave * 32 + mt * 16 + quad * 4;
#pragma unroll
      for (int r = 0; r < 4; r++) {
        Qs[(row + r) * QKS + col] = f2bf(acc[mt][3 * h + 0][r] * QSCALE);
        Ks[(row + r) * QKS + col] = f2bf(acc[mt][3 * h + 1][r]);
        Vt[col * VTS + row + r] = f2bf(acc[mt][3 * h + 2][r]);
      }
    }
    __syncthreads();

    const int q0 = wave * 32;
    short4v bq[2];
    float mqv[2];
#pragma unroll
    for (int qt = 0; qt < 2; qt++) {
      bq[qt] = *(const short4v*)(Qs + (q0 + qt * 16 + col) * QKS + quad * 4);
      mqv[qt] = m_s[q0 + qt * 16 + col];
    }

    floatx4 oacc[2] = {};
    floatx4 lacc[2] = {};
    if (allones)
      attn_loop2<false>(Ks, Vt, bq, mqv, m_s, oacc, lacc, col, quad);
    else
      attn_loop2<true>(Ks, Vt, bq, mqv, m_s, oacc, lacc, col, quad);

    __syncthreads();  // all waves out of attn before ot overlays Qs/Ks
#pragma unroll
    for (int qt = 0; qt < 2; qt++) {
      if (quad == 0) l_s[q0 + qt * 16 + col] = lacc[qt][0];
#pragma unroll
      for (int r = 0; r < 4; r++)
        ot[(quad * 4 + r) * 257 + q0 + qt * 16 + col] = oacc[qt][r];
    }
    __syncthreads();

    // epilogue: thread t -> q-row t>>1, features hb..hb+8; 32B coalesced
    const int row = t >> 1;
    const int hb = (t & 1) * 8;
    float l = l_s[row];
    float* op = out + ((size_t)b * 256 + row) * 1024 + (c0 + h) * 16 + hb;
    float o[8];
    if (allones || l > 0.f) {
      float inv = 1.0f / l;
#pragma unroll
      for (int j = 0; j < 8; j++) o[j] = ot[(hb + j) * 257 + row] * inv;
    } else {
      // fully-masked row: reference softmax of uniform -1e9 -> mean of V
#pragma unroll
      for (int j = 0; j < 8; j++) o[j] = 0.f;
      for (int k = 0; k < 256; k++)
#pragma unroll
        for (int j = 0; j < 8; j++) o[j] += bf2f(Vt[(hb + j) * VTS + k]);
#pragma unroll
      for (int j = 0; j < 8; j++) o[j] *= (1.0f / 256.0f);
    }
#pragma unroll
    for (int g = 0; g < 2; g++) {
      float4 r;
      r.x = o[g * 4 + 0]; r.y = o[g * 4 + 1]; r.z = o[g * 4 + 2]; r.w = o[g * 4 + 3];
      *(float4*)(op + g * 4) = r;
    }
  }
}

// ---------------------------------------------------------------------------
// Launch
// ---------------------------------------------------------------------------
extern "C" void kernel_launch(void* const* d_in, const int* in_sizes, int n_in,
                              void* d_out, int out_size, void* d_ws, size_t ws_size,
                              hipStream_t stream) {
  const float* x    = (const float*)d_in[0];  // [32,256,1024]
  const float* mask = (const float*)d_in[1];  // [32,256]
  const float* Wq   = (const float*)d_in[2];  // [1024,1024]
  const float* Wk   = (const float*)d_in[3];
  const float* Wv   = (const float*)d_in[4];
  float* out = (float*)d_out;

  u16* XB = (u16*)d_ws;                       // [8192][1024] bf16
  u16* WB = XB + (size_t)8192 * 1024;         // [3072][1024] (Wq,Wk,Wv stacked)

  cast_all<<<11264, 256, 0, stream>>>(x, Wq, Wk, Wv, XB, WB);
  fused_qkv_attn<<<1024, 512, 0, stream>>>(XB, WB, mask, out);
}